// Round 4
// baseline (2073.988 us; speedup 1.0000x reference)
//
#include <hip/hip_runtime.h>
#include <hip/hip_bf16.h>

#define N_NODES 50000
#define N_EDGES 1600000
#define TILE    128

typedef __bf16 bf16x8 __attribute__((ext_vector_type(8)));
typedef __bf16 bf16x4 __attribute__((ext_vector_type(4)));
typedef float  f32x4  __attribute__((ext_vector_type(4)));

static __device__ __forceinline__ bf16x8 ld8(const __bf16* p) {
  return *reinterpret_cast<const bf16x8*>(p);
}
static __device__ __forceinline__ void st8(__bf16* p, bf16x8 v) {
  *reinterpret_cast<bf16x8*>(p) = v;
}

// async global->LDS DMA, 16B per lane; dest = wave-uniform base + lane*16
static __device__ __forceinline__ void async16(const void* g, void* l) {
  auto gp = (const __attribute__((address_space(1))) unsigned int*)(unsigned long long)g;
  auto lp = (__attribute__((address_space(3))) unsigned int*)(unsigned int)(unsigned long long)l;
  __builtin_amdgcn_global_load_lds(gp, lp, 16, 0, 0);
}

// ---- prep: transpose weights to [n][k] bf16 (B-operand layout) ----
__global__ __launch_bounds__(256) void k_prep_w(
    const float* __restrict__ Wi, const float* __restrict__ Wu,
    const float* __restrict__ Wf,
    __bf16* __restrict__ WiT, __bf16* __restrict__ WuT, __bf16* __restrict__ WfT)
{
  int g = blockIdx.x * 256 + threadIdx.x;
  if (g < 160 * 128) {
    int n = g / 160, k = g % 160;
    WiT[g] = (__bf16)Wi[k * 128 + n];
  } else if (g < 160 * 128 + 128 * 128) {
    int gg = g - 160 * 128;
    int n = gg / 128, k = gg % 128;
    WuT[gg] = (__bf16)Wu[k * 128 + n];
  } else if (g < 160 * 128 + 128 * 128 + 256 * 128) {
    int gg = g - (160 * 128 + 128 * 128);
    int n = gg / 256, k = gg % 256;
    WfT[gg] = (__bf16)Wf[k * 128 + n];
  }
}

// ---- f32 -> bf16 bulk convert ----
__global__ __launch_bounds__(256) void k_cvt(
    const float* __restrict__ in, __bf16* __restrict__ out, long n)
{
  long i = ((long)blockIdx.x * 256 + threadIdx.x) * 8;
  if (i + 8 <= n) {
    f32x4 f0 = *(const f32x4*)(in + i);
    f32x4 f1 = *(const f32x4*)(in + i + 4);
    bf16x8 o;
#pragma unroll
    for (int j = 0; j < 4; ++j) { o[j] = (__bf16)f0[j]; o[4 + j] = (__bf16)f1[j]; }
    st8(out + i, o);
  }
}

// ---- CSR build ----
__global__ __launch_bounds__(256) void k_hist(
    const int* __restrict__ edst, int* __restrict__ cnt)
{
  int e = blockIdx.x * 256 + threadIdx.x;
  if (e < N_EDGES) atomicAdd(&cnt[edst[e]], 1);
}

__global__ __launch_bounds__(1024) void k_scan1(
    int* __restrict__ cnt, int* __restrict__ bsum, int n)
{
  __shared__ int sm[1024];
  const int tid = threadIdx.x;
  int i = blockIdx.x * 1024 + tid;
  int v = (i < n) ? cnt[i] : 0;
  sm[tid] = v;
  __syncthreads();
  for (int off = 1; off < 1024; off <<= 1) {
    int t = (tid >= off) ? sm[tid - off] : 0;
    __syncthreads();
    sm[tid] += t;
    __syncthreads();
  }
  if (i < n) cnt[i] = sm[tid] - v;
  if (tid == 1023) bsum[blockIdx.x] = sm[1023];
}

__global__ __launch_bounds__(64) void k_scan2(int* __restrict__ bsum, int nb)
{
  if (threadIdx.x == 0) {
    int acc = 0;
    for (int k = 0; k < nb; ++k) { int t = bsum[k]; bsum[k] = acc; acc += t; }
  }
}

__global__ __launch_bounds__(256) void k_scan3(
    const int* __restrict__ cnt, const int* __restrict__ bsum,
    int* __restrict__ cursor, int n)
{
  int i = blockIdx.x * 256 + threadIdx.x;
  if (i < n) cursor[i] = cnt[i] + bsum[i >> 10];
}

__global__ __launch_bounds__(256) void k_fill(
    const int* __restrict__ edst, int* __restrict__ cursor, int* __restrict__ eidx)
{
  int e = blockIdx.x * 256 + threadIdx.x;
  if (e < N_EDGES) {
    int p = atomicAdd(&cursor[edst[e]], 1);
    eidx[p] = e;
  }
}

// ---- gather-aggregate: aggbf[n] = sum over incoming edges h[e] ----
__global__ __launch_bounds__(256) void k_agg(
    const __bf16* __restrict__ h, const int* __restrict__ cnt,
    const int* __restrict__ bsum, const int* __restrict__ eidx,
    __bf16* __restrict__ aggbf)
{
  const int wave = threadIdx.x >> 6;
  const int node = blockIdx.x * 4 + wave;
  const int lane = threadIdx.x & 63;
  const int g = lane >> 3, c8 = lane & 7;
  const int s = cnt[node] + bsum[node >> 10];
  const int e = (node + 1 < N_NODES) ? (cnt[node + 1] + bsum[(node + 1) >> 10]) : N_EDGES;
  const int deg = e - s;

  float a[16] = {};
  if (deg > 0) {
    const int* bucket = eidx + s;
    const int nit = (deg + 7) >> 3;
    int j0 = g;
    int e0 = bucket[(j0 < deg) ? j0 : 0];
    int e1 = bucket[(j0 + 8 < deg) ? j0 + 8 : 0];
    bool v0 = (j0 < deg), v1 = (j0 + 8 < deg);
    for (int it = 0; it < nit; ++it) {
      const int j2 = j0 + 16;
      const int e2 = bucket[(j2 < deg) ? j2 : 0];
      const __bf16* hp = h + (long)e0 * 128 + c8 * 16;
      bf16x8 r0 = ld8(hp), r1 = ld8(hp + 8);
#pragma unroll
      for (int k = 0; k < 8; ++k) {
        a[k]     += v0 ? (float)r0[k] : 0.f;
        a[8 + k] += v0 ? (float)r1[k] : 0.f;
      }
      e0 = e1; v0 = v1;
      e1 = e2; v1 = (j2 < deg);
      j0 += 8;
    }
  }
#pragma unroll
  for (int k = 0; k < 16; ++k) {
    a[k] += __shfl_xor(a[k], 8, 64);
    a[k] += __shfl_xor(a[k], 16, 64);
    a[k] += __shfl_xor(a[k], 32, 64);
  }
  if (g == 0) {
    bf16x8 o0, o1;
#pragma unroll
    for (int k = 0; k < 8; ++k) { o0[k] = (__bf16)a[k]; o1[k] = (__bf16)a[8 + k]; }
    st8(aggbf + (long)node * 128 + c8 * 16, o0);
    st8(aggbf + (long)node * 128 + c8 * 16 + 8, o1);
  }
}

// ---- node GEMM (swapped operands): lane dim = node row, reg dim = col ----
__global__ __launch_bounds__(256) void k_nodegemm(
    const __bf16* __restrict__ A, const __bf16* __restrict__ BT, const int ldb,
    const float* __restrict__ bias, __bf16* __restrict__ outb, const int nrows)
{
  const int tid = threadIdx.x;
  const int lane = tid & 63, wave = tid >> 6;
  const int l15 = lane & 15, quad = lane >> 4;
  const int wm = wave >> 1, wn = wave & 1;
  const int base = blockIdx.x * TILE;

  int rowm[4];
#pragma unroll
  for (int ms = 0; ms < 4; ++ms) {
    int nd = base + wm * 64 + ms * 16 + l15;
    rowm[ms] = nd < nrows ? nd : (nrows - 1);
  }
  f32x4 acc[4][4] = {};
#pragma unroll
  for (int kit = 0; kit < 4; ++kit) {
    const int koff = kit * 32 + quad * 8;
    bf16x8 b[4];
#pragma unroll
    for (int ms = 0; ms < 4; ++ms)
      b[ms] = ld8(A + (long)rowm[ms] * 128 + koff);
#pragma unroll
    for (int ns = 0; ns < 4; ++ns) {
      bf16x8 a = ld8(BT + (wn * 64 + ns * 16 + l15) * ldb + koff);
#pragma unroll
      for (int ms = 0; ms < 4; ++ms)
        acc[ms][ns] = __builtin_amdgcn_mfma_f32_16x16x32_bf16(a, b[ms], acc[ms][ns], 0, 0, 0);
    }
  }
#pragma unroll
  for (int ns = 0; ns < 4; ++ns) {
    const int col = wn * 64 + ns * 16 + quad * 4;
    const f32x4 bv = *(const f32x4*)(bias + col);
#pragma unroll
    for (int ms = 0; ms < 4; ++ms) {
      const int node = base + wm * 64 + ms * 16 + l15;
      if (node < nrows) {
        bf16x4 o;
#pragma unroll
        for (int j = 0; j < 4; ++j) o[j] = (__bf16)(acc[ms][ns][j] + bv[j]);
        *(bf16x4*)(outb + (long)node * 128 + col) = o;
      }
    }
  }
}

// ---- init: h0 = relu(q[src] + ef @ Wi[128:160]) ----
// 8-wave split of the 128-edge tile; round-0 C layout; all q-gathers
// prefetched at start; ONE barrier; direct global f32 ef reads.
__global__ __launch_bounds__(512) void k_init(
    const float* __restrict__ ef, const int* __restrict__ esrc,
    const __bf16* __restrict__ WiT, const __bf16* __restrict__ q,
    __bf16* __restrict__ h)
{
  __shared__ __align__(16) __bf16 cbuf[128 * 128];  // 32KB C roundtrip
  const int tid = threadIdx.x;
  const int lane = tid & 63, wave = tid >> 6;
  const int l15 = lane & 15, quad = lane >> 4;
  const int wm = wave >> 2, wn = wave & 3;   // wm: row half, wn: 32-col quarter
  const long base = (long)blockIdx.x * TILE;

  // epilogue-mapped q gathers, in flight across the MFMA phase
  const int c15 = tid & 15, rbase = tid >> 4;        // rbase 0..31
  int srcv[4];
#pragma unroll
  for (int i = 0; i < 4; ++i) srcv[i] = esrc[base + i * 32 + rbase];
  bf16x8 gp[4];
#pragma unroll
  for (int i = 0; i < 4; ++i) gp[i] = ld8(q + (long)srcv[i] * 128 + c15 * 8);

  // A fragments straight from global ef (f32), convert to bf16
  f32x4 acc[4][2] = {};
  {
    bf16x8 a[4];
#pragma unroll
    for (int ms = 0; ms < 4; ++ms) {
      const int rm = wm * 64 + ms * 16 + l15;
      f32x4 f0 = *(const f32x4*)(ef + (base + rm) * 32 + quad * 8);
      f32x4 f1 = *(const f32x4*)(ef + (base + rm) * 32 + quad * 8 + 4);
      bf16x8 v;
#pragma unroll
      for (int j = 0; j < 4; ++j) { v[j] = (__bf16)f0[j]; v[4 + j] = (__bf16)f1[j]; }
      a[ms] = v;
    }
#pragma unroll
    for (int ns = 0; ns < 2; ++ns) {
      bf16x8 b = ld8(WiT + (wn * 32 + ns * 16 + l15) * 160 + 128 + quad * 8);
#pragma unroll
      for (int ms = 0; ms < 4; ++ms)
        acc[ms][ns] = __builtin_amdgcn_mfma_f32_16x16x32_bf16(a[ms], b, acc[ms][ns], 0, 0, 0);
    }
  }

  // C -> LDS (XOR-swizzled for 16B reads)
#pragma unroll
  for (int ns = 0; ns < 2; ++ns) {
    const int col = wn * 32 + ns * 16 + l15;
#pragma unroll
    for (int ms = 0; ms < 4; ++ms) {
      const int r0 = wm * 64 + ms * 16 + quad * 4;
#pragma unroll
      for (int r = 0; r < 4; ++r) {
        const int row = r0 + r;
        cbuf[row * 128 + (((col >> 3) ^ (row & 15)) * 8) + (col & 7)] = (__bf16)acc[ms][ns][r];
      }
    }
  }
  __syncthreads();

#pragma unroll
  for (int i = 0; i < 4; ++i) {
    const int row = i * 32 + rbase;
    bf16x8 cv = ld8(cbuf + row * 128 + ((c15 ^ (row & 15)) * 8));
    bf16x8 o;
#pragma unroll
    for (int j = 0; j < 8; ++j) {
      float v = (float)gp[i][j] + (float)cv[j];
      o[j] = (__bf16)(v > 0.f ? v : 0.f);
    }
    st8(h + (base + row) * 128 + c15 * 8, o);
  }
}

// ---- update: h[e] = relu(gW[src[e]] - (h@Wu)[e^1] + h[e]) ----
// 8-wave split, SINGLE 32KB LDS buffer (stage reused as C roundtrip) ->
// 3 blocks/CU. Residual hv read from global h (L2-hot, issued right after
// the MFMA loop so latency drains at the middle barrier). 3 barriers.
__global__ __launch_bounds__(512) void k_update(
    __bf16* __restrict__ h, const int* __restrict__ esrc,
    const __bf16* __restrict__ WuT, const __bf16* __restrict__ gW)
{
  __shared__ __align__(16) __bf16 smem[128 * 128];  // 32KB: h stage, then hWu
  const int tid = threadIdx.x;
  const int lane = tid & 63, wave = tid >> 6;
  const int l15 = lane & 15, quad = lane >> 4;
  const int wm = wave >> 2, wn = wave & 3;   // wm: row half, wn: 32-col quarter
  const long base = (long)blockIdx.x * TILE;

  // src indices first (independent, coalesced)
  const int c15 = tid & 15, rbase = tid >> 4;        // rbase 0..31
  int srcv[4];
#pragma unroll
  for (int i = 0; i < 4; ++i) srcv[i] = esrc[base + i * 32 + rbase];

  // stage h tile: each wave 16 rows, 16B-chunk XOR swizzle
#pragma unroll
  for (int j = 0; j < 4; ++j) {
    const int r = wave * 16 + j * 4 + (lane >> 4);
    const int cd = (lane & 15) ^ (r & 15);
    async16(h + (base + r) * 128 + cd * 8, smem + (wave * 16 + j * 4) * 128);
  }

  // all gW gathers in flight before the barrier
  bf16x8 gp[4];
#pragma unroll
  for (int i = 0; i < 4; ++i) gp[i] = ld8(gW + (long)srcv[i] * 128 + c15 * 8);

  __syncthreads();  // [1] stage complete

  f32x4 acc[4][2] = {};
#pragma unroll
  for (int kit = 0; kit < 4; ++kit) {
    bf16x8 a[4];
#pragma unroll
    for (int ms = 0; ms < 4; ++ms) {
      const int rm = wm * 64 + ms * 16 + l15;
      a[ms] = ld8(smem + rm * 128 + (((kit * 4 + quad) ^ l15) * 8));
    }
#pragma unroll
    for (int ns = 0; ns < 2; ++ns) {
      bf16x8 b = ld8(WuT + (wn * 32 + ns * 16 + l15) * 128 + kit * 32 + quad * 8);
#pragma unroll
      for (int ms = 0; ms < 4; ++ms)
        acc[ms][ns] = __builtin_amdgcn_mfma_f32_16x16x32_bf16(a[ms], b, acc[ms][ns], 0, 0, 0);
    }
  }

  // residual rows from global h (L2-hot; drains at the next barrier)
  bf16x8 hv[4];
#pragma unroll
  for (int i = 0; i < 4; ++i)
    hv[i] = ld8(h + (base + i * 32 + rbase) * 128 + c15 * 8);

  __syncthreads();  // [2] all A-fragment reads done; smem can be overwritten

  // hWu -> smem (XOR-swizzled)
#pragma unroll
  for (int ns = 0; ns < 2; ++ns) {
    const int col = wn * 32 + ns * 16 + l15;
#pragma unroll
    for (int ms = 0; ms < 4; ++ms) {
      const int r0 = wm * 64 + ms * 16 + quad * 4;
#pragma unroll
      for (int r = 0; r < 4; ++r) {
        const int row = r0 + r;
        smem[row * 128 + (((col >> 3) ^ (row & 15)) * 8) + (col & 7)] = (__bf16)acc[ms][ns][r];
      }
    }
  }
  __syncthreads();  // [3] C tile visible

#pragma unroll
  for (int i = 0; i < 4; ++i) {
    const int row = i * 32 + rbase;
    const int rowr = row ^ 1;  // rev(e) = e^1, pair-aligned within tile
    bf16x8 cv = ld8(smem + rowr * 128 + ((c15 ^ (rowr & 15)) * 8));
    bf16x8 o;
#pragma unroll
    for (int j = 0; j < 8; ++j) {
      float v = (float)gp[i][j] - (float)cv[j] + (float)hv[i][j];
      o[j] = (__bf16)(v > 0.f ? v : 0.f);
    }
    st8(h + (base + row) * 128 + c15 * 8, o);
  }
}

// ---- final (swapped): out = relu([nf | agg(h4)] @ Wf + bf), 16B f32 stores ----
__global__ __launch_bounds__(256) void k_final(
    const __bf16* __restrict__ nfbf, const __bf16* __restrict__ aggbf,
    const __bf16* __restrict__ WfT, const float* __restrict__ bfb,
    float* __restrict__ out)
{
  const int tid = threadIdx.x;
  const int lane = tid & 63, wave = tid >> 6;
  const int l15 = lane & 15, quad = lane >> 4;
  const int wm = wave >> 1, wn = wave & 1;
  const int base = blockIdx.x * TILE;

  int rowm[4];
#pragma unroll
  for (int ms = 0; ms < 4; ++ms) {
    int nd = base + wm * 64 + ms * 16 + l15;
    rowm[ms] = nd < N_NODES ? nd : (N_NODES - 1);
  }
  f32x4 acc[4][4] = {};
#pragma unroll
  for (int kit = 0; kit < 8; ++kit) {
    const int koff = kit * 32 + quad * 8;
    bf16x8 b[4];
#pragma unroll
    for (int ms = 0; ms < 4; ++ms)
      b[ms] = (kit < 4) ? ld8(nfbf + (long)rowm[ms] * 128 + koff)
                        : ld8(aggbf + (long)rowm[ms] * 128 + (koff - 128));
#pragma unroll
    for (int ns = 0; ns < 4; ++ns) {
      bf16x8 a = ld8(WfT + (wn * 64 + ns * 16 + l15) * 256 + koff);
#pragma unroll
      for (int ms = 0; ms < 4; ++ms)
        acc[ms][ns] = __builtin_amdgcn_mfma_f32_16x16x32_bf16(a, b[ms], acc[ms][ns], 0, 0, 0);
    }
  }
#pragma unroll
  for (int ns = 0; ns < 4; ++ns) {
    const int col = wn * 64 + ns * 16 + quad * 4;
    const f32x4 bv = *(const f32x4*)(bfb + col);
#pragma unroll
    for (int ms = 0; ms < 4; ++ms) {
      const int node = base + wm * 64 + ms * 16 + l15;
      if (node < N_NODES) {
        f32x4 o;
#pragma unroll
        for (int j = 0; j < 4; ++j) {
          float v = acc[ms][ns][j] + bv[j];
          o[j] = v > 0.f ? v : 0.f;
        }
        *(f32x4*)(out + (long)node * 128 + col) = o;
      }
    }
  }
}

extern "C" void kernel_launch(void* const* d_in, const int* in_sizes, int n_in,
                              void* d_out, int out_size, void* d_ws, size_t ws_size,
                              hipStream_t stream) {
  const float* nf   = (const float*)d_in[0];
  const float* ef   = (const float*)d_in[1];
  const int*   esrc = (const int*)d_in[2];
  const int*   edst = (const int*)d_in[3];
  const float* Wi   = (const float*)d_in[4];
  const float* bi   = (const float*)d_in[5];
  const float* Wu   = (const float*)d_in[6];
  const float* bu   = (const float*)d_in[7];
  const float* Wf   = (const float*)d_in[8];
  const float* bfb  = (const float*)d_in[9];
  float* out = (float*)d_out;

  char* ws = (char*)d_ws;
  __bf16* h      = (__bf16*)(ws);                  // 409,600,000 B
  __bf16* aggbf  = (__bf16*)(ws + 409600000L);     //  12,800,000 B
  __bf16* nfbf   = (__bf16*)(ws + 422400000L);     //  12,800,000 B
  __bf16* WiT    = (__bf16*)(ws + 435200000L);     //      40,960 B
  __bf16* WuT    = (__bf16*)(ws + 435240960L);     //      32,768 B
  __bf16* WfT    = (__bf16*)(ws + 435273728L);     //      65,536 B
  int*    cnt    = (int*)(ws + 435339264L);        //     200,000 B
  int*    cursor = (int*)(ws + 435539264L);        //     200,000 B
  int*    bsum   = (int*)(ws + 435739264L);        //         256 B
  int*    eidx   = (int*)(ws + 435739520L);        //   6,400,000 B
  __bf16* g      = (__bf16*)(ws + 442139520L);     //  12,800,000 B (q then gW, bf16)

  const long NV = (long)N_NODES * 128;
  const int  NGB = (N_NODES + TILE - 1) / TILE;    // 391

  hipLaunchKernelGGL(k_prep_w, dim3(272), dim3(256), 0, stream, Wi, Wu, Wf, WiT, WuT, WfT);
  hipLaunchKernelGGL(k_cvt, dim3(3125), dim3(256), 0, stream, nf, nfbf, NV);
  // CSR build
  hipMemsetAsync(cnt, 0, 200000, stream);
  hipLaunchKernelGGL(k_hist, dim3(N_EDGES / 256), dim3(256), 0, stream, edst, cnt);
  hipLaunchKernelGGL(k_scan1, dim3(49), dim3(1024), 0, stream, cnt, bsum, N_NODES);
  hipLaunchKernelGGL(k_scan2, dim3(1), dim3(64), 0, stream, bsum, 49);
  hipLaunchKernelGGL(k_scan3, dim3(196), dim3(256), 0, stream, cnt, bsum, cursor, N_NODES);
  hipLaunchKernelGGL(k_fill, dim3(N_EDGES / 256), dim3(256), 0, stream, edst, cursor, eidx);

  // q = nf @ Wi[0:128] + bi (per node, bf16), then per-edge init with K=32 ef slice
  hipLaunchKernelGGL(k_nodegemm, dim3(NGB), dim3(256), 0, stream, nfbf, WiT, 160, bi, g, N_NODES);
  hipLaunchKernelGGL(k_init, dim3(N_EDGES / TILE), dim3(512), 0, stream, ef, esrc, WiT, g, h);

  for (int t = 0; t < 4; ++t) {
    hipLaunchKernelGGL(k_agg, dim3(N_NODES / 4), dim3(256), 0, stream, h, cnt, bsum, eidx, aggbf);
    hipLaunchKernelGGL(k_nodegemm, dim3(NGB), dim3(256), 0, stream, aggbf, WuT, 128, bu, g, N_NODES);
    hipLaunchKernelGGL(k_update, dim3(N_EDGES / TILE), dim3(512), 0, stream, h, esrc, WuT, g);
  }
  hipLaunchKernelGGL(k_agg, dim3(N_NODES / 4), dim3(256), 0, stream, h, cnt, bsum, eidx, aggbf);
  hipLaunchKernelGGL(k_final, dim3(NGB), dim3(256), 0, stream, nfbf, aggbf, WfT, bfb, out);
}

// Round 5
// 2025.932 us; speedup vs baseline: 1.0237x; 1.0237x over previous
//
#include <hip/hip_runtime.h>
#include <hip/hip_bf16.h>

#define N_NODES 50000
#define N_EDGES 1600000
#define TILE    128

typedef __bf16 bf16x8 __attribute__((ext_vector_type(8)));
typedef __bf16 bf16x4 __attribute__((ext_vector_type(4)));
typedef float  f32x4  __attribute__((ext_vector_type(4)));

static __device__ __forceinline__ bf16x8 ld8(const __bf16* p) {
  return *reinterpret_cast<const bf16x8*>(p);
}
static __device__ __forceinline__ void st8(__bf16* p, bf16x8 v) {
  *reinterpret_cast<bf16x8*>(p) = v;
}

// async global->LDS DMA, 16B per lane; dest = wave-uniform base + lane*16
static __device__ __forceinline__ void async16(const void* g, void* l) {
  auto gp = (const __attribute__((address_space(1))) unsigned int*)(unsigned long long)g;
  auto lp = (__attribute__((address_space(3))) unsigned int*)(unsigned int)(unsigned long long)l;
  __builtin_amdgcn_global_load_lds(gp, lp, 16, 0, 0);
}

// ---- prep: transpose weights to [n][k] bf16 (B-operand layout) ----
__global__ __launch_bounds__(256) void k_prep_w(
    const float* __restrict__ Wi, const float* __restrict__ Wu,
    const float* __restrict__ Wf,
    __bf16* __restrict__ WiT, __bf16* __restrict__ WuT, __bf16* __restrict__ WfT)
{
  int g = blockIdx.x * 256 + threadIdx.x;
  if (g < 160 * 128) {
    int n = g / 160, k = g % 160;
    WiT[g] = (__bf16)Wi[k * 128 + n];
  } else if (g < 160 * 128 + 128 * 128) {
    int gg = g - 160 * 128;
    int n = gg / 128, k = gg % 128;
    WuT[gg] = (__bf16)Wu[k * 128 + n];
  } else if (g < 160 * 128 + 128 * 128 + 256 * 128) {
    int gg = g - (160 * 128 + 128 * 128);
    int n = gg / 256, k = gg % 256;
    WfT[gg] = (__bf16)Wf[k * 128 + n];
  }
}

// ---- f32 -> bf16 bulk convert ----
__global__ __launch_bounds__(256) void k_cvt(
    const float* __restrict__ in, __bf16* __restrict__ out, long n)
{
  long i = ((long)blockIdx.x * 256 + threadIdx.x) * 8;
  if (i + 8 <= n) {
    f32x4 f0 = *(const f32x4*)(in + i);
    f32x4 f1 = *(const f32x4*)(in + i + 4);
    bf16x8 o;
#pragma unroll
    for (int j = 0; j < 4; ++j) { o[j] = (__bf16)f0[j]; o[4 + j] = (__bf16)f1[j]; }
    st8(out + i, o);
  }
}

// ---- CSR build ----
__global__ __launch_bounds__(256) void k_hist(
    const int* __restrict__ edst, int* __restrict__ cnt)
{
  int e = blockIdx.x * 256 + threadIdx.x;
  if (e < N_EDGES) atomicAdd(&cnt[edst[e]], 1);
}

__global__ __launch_bounds__(1024) void k_scan1(
    int* __restrict__ cnt, int* __restrict__ bsum, int n)
{
  __shared__ int sm[1024];
  const int tid = threadIdx.x;
  int i = blockIdx.x * 1024 + tid;
  int v = (i < n) ? cnt[i] : 0;
  sm[tid] = v;
  __syncthreads();
  for (int off = 1; off < 1024; off <<= 1) {
    int t = (tid >= off) ? sm[tid - off] : 0;
    __syncthreads();
    sm[tid] += t;
    __syncthreads();
  }
  if (i < n) cnt[i] = sm[tid] - v;
  if (tid == 1023) bsum[blockIdx.x] = sm[1023];
}

__global__ __launch_bounds__(64) void k_scan2(int* __restrict__ bsum, int nb)
{
  if (threadIdx.x == 0) {
    int acc = 0;
    for (int k = 0; k < nb; ++k) { int t = bsum[k]; bsum[k] = acc; acc += t; }
  }
}

__global__ __launch_bounds__(256) void k_scan3(
    const int* __restrict__ cnt, const int* __restrict__ bsum,
    int* __restrict__ cursor, int n)
{
  int i = blockIdx.x * 256 + threadIdx.x;
  if (i < n) cursor[i] = cnt[i] + bsum[i >> 10];
}

__global__ __launch_bounds__(256) void k_fill(
    const int* __restrict__ edst, int* __restrict__ cursor, int* __restrict__ eidx)
{
  int e = blockIdx.x * 256 + threadIdx.x;
  if (e < N_EDGES) {
    int p = atomicAdd(&cursor[edst[e]], 1);
    eidx[p] = e;
  }
}

// ---- gather-aggregate: aggbf[n] = sum over incoming edges h[e] ----
// row-data prefetch 1-deep (indices 2-deep); invalid lane-groups read a
// 256B zero row -> unconditional accumulate (no per-element cndmask).
__global__ __launch_bounds__(256) void k_agg(
    const __bf16* __restrict__ h, const int* __restrict__ cnt,
    const int* __restrict__ bsum, const int* __restrict__ eidx,
    const __bf16* __restrict__ zrow, __bf16* __restrict__ aggbf)
{
  const int wave = threadIdx.x >> 6;
  const int node = blockIdx.x * 4 + wave;
  const int lane = threadIdx.x & 63;
  const int g = lane >> 3, c8 = lane & 7;
  const int s = cnt[node] + bsum[node >> 10];
  const int e = (node + 1 < N_NODES) ? (cnt[node + 1] + bsum[(node + 1) >> 10]) : N_EDGES;
  const int deg = e - s;

  float a[16] = {};
  if (deg > 0) {
    const int* bucket = eidx + s;
    const int nit = (deg + 7) >> 3;
    int j0 = g;
    int e0 = bucket[(j0 < deg) ? j0 : 0];
    int e1 = bucket[(j0 + 8 < deg) ? j0 + 8 : 0];
    bool v0 = (j0 < deg), v1 = (j0 + 8 < deg);
    // current row in flight
    const __bf16* p0 = v0 ? (h + (long)e0 * 128 + c8 * 16) : zrow;
    bf16x8 r0 = ld8(p0), r1 = ld8(p0 + 8);
    for (int it = 0; it < nit; ++it) {
      // prefetch next iteration's index and row
      const int j2 = j0 + 16;
      const int e2 = bucket[(j2 < deg) ? j2 : 0];
      const __bf16* p1 = v1 ? (h + (long)e1 * 128 + c8 * 16) : zrow;
      bf16x8 n0 = ld8(p1), n1 = ld8(p1 + 8);
      // accumulate current (unconditional: zrow contributes zeros)
#pragma unroll
      for (int k = 0; k < 8; ++k) {
        a[k]     += (float)r0[k];
        a[8 + k] += (float)r1[k];
      }
      r0 = n0; r1 = n1;
      e1 = e2; v1 = (j2 < deg);
      j0 += 8;
    }
  }
#pragma unroll
  for (int k = 0; k < 16; ++k) {
    a[k] += __shfl_xor(a[k], 8, 64);
    a[k] += __shfl_xor(a[k], 16, 64);
    a[k] += __shfl_xor(a[k], 32, 64);
  }
  if (g == 0) {
    bf16x8 o0, o1;
#pragma unroll
    for (int k = 0; k < 8; ++k) { o0[k] = (__bf16)a[k]; o1[k] = (__bf16)a[8 + k]; }
    st8(aggbf + (long)node * 128 + c8 * 16, o0);
    st8(aggbf + (long)node * 128 + c8 * 16 + 8, o1);
  }
}

// ---- node GEMM (swapped operands): lane dim = node row, reg dim = col ----
__global__ __launch_bounds__(256) void k_nodegemm(
    const __bf16* __restrict__ A, const __bf16* __restrict__ BT, const int ldb,
    const float* __restrict__ bias, __bf16* __restrict__ outb, const int nrows)
{
  const int tid = threadIdx.x;
  const int lane = tid & 63, wave = tid >> 6;
  const int l15 = lane & 15, quad = lane >> 4;
  const int wm = wave >> 1, wn = wave & 1;
  const int base = blockIdx.x * TILE;

  int rowm[4];
#pragma unroll
  for (int ms = 0; ms < 4; ++ms) {
    int nd = base + wm * 64 + ms * 16 + l15;
    rowm[ms] = nd < nrows ? nd : (nrows - 1);
  }
  f32x4 acc[4][4] = {};
#pragma unroll
  for (int kit = 0; kit < 4; ++kit) {
    const int koff = kit * 32 + quad * 8;
    bf16x8 b[4];
#pragma unroll
    for (int ms = 0; ms < 4; ++ms)
      b[ms] = ld8(A + (long)rowm[ms] * 128 + koff);
#pragma unroll
    for (int ns = 0; ns < 4; ++ns) {
      bf16x8 a = ld8(BT + (wn * 64 + ns * 16 + l15) * ldb + koff);
#pragma unroll
      for (int ms = 0; ms < 4; ++ms)
        acc[ms][ns] = __builtin_amdgcn_mfma_f32_16x16x32_bf16(a, b[ms], acc[ms][ns], 0, 0, 0);
    }
  }
#pragma unroll
  for (int ns = 0; ns < 4; ++ns) {
    const int col = wn * 64 + ns * 16 + quad * 4;
    const f32x4 bv = *(const f32x4*)(bias + col);
#pragma unroll
    for (int ms = 0; ms < 4; ++ms) {
      const int node = base + wm * 64 + ms * 16 + l15;
      if (node < nrows) {
        bf16x4 o;
#pragma unroll
        for (int j = 0; j < 4; ++j) o[j] = (__bf16)(acc[ms][ns][j] + bv[j]);
        *(bf16x4*)(outb + (long)node * 128 + col) = o;
      }
    }
  }
}

// ---- init: h0 = relu(q[src] + ef @ Wi[128:160]) ----
// 8-wave split of the 128-edge tile; round-0 C layout; all q-gathers
// prefetched at start; ONE barrier; direct global f32 ef reads.
__global__ __launch_bounds__(512) void k_init(
    const float* __restrict__ ef, const int* __restrict__ esrc,
    const __bf16* __restrict__ WiT, const __bf16* __restrict__ q,
    __bf16* __restrict__ h)
{
  __shared__ __align__(16) __bf16 cbuf[128 * 128];  // 32KB C roundtrip
  const int tid = threadIdx.x;
  const int lane = tid & 63, wave = tid >> 6;
  const int l15 = lane & 15, quad = lane >> 4;
  const int wm = wave >> 2, wn = wave & 3;   // wm: row half, wn: 32-col quarter
  const long base = (long)blockIdx.x * TILE;

  // epilogue-mapped q gathers, in flight across the MFMA phase
  const int c15 = tid & 15, rbase = tid >> 4;        // rbase 0..31
  int srcv[4];
#pragma unroll
  for (int i = 0; i < 4; ++i) srcv[i] = esrc[base + i * 32 + rbase];
  bf16x8 gp[4];
#pragma unroll
  for (int i = 0; i < 4; ++i) gp[i] = ld8(q + (long)srcv[i] * 128 + c15 * 8);

  // A fragments straight from global ef (f32), convert to bf16
  f32x4 acc[4][2] = {};
  {
    bf16x8 a[4];
#pragma unroll
    for (int ms = 0; ms < 4; ++ms) {
      const int rm = wm * 64 + ms * 16 + l15;
      f32x4 f0 = *(const f32x4*)(ef + (base + rm) * 32 + quad * 8);
      f32x4 f1 = *(const f32x4*)(ef + (base + rm) * 32 + quad * 8 + 4);
      bf16x8 v;
#pragma unroll
      for (int j = 0; j < 4; ++j) { v[j] = (__bf16)f0[j]; v[4 + j] = (__bf16)f1[j]; }
      a[ms] = v;
    }
#pragma unroll
    for (int ns = 0; ns < 2; ++ns) {
      bf16x8 b = ld8(WiT + (wn * 32 + ns * 16 + l15) * 160 + 128 + quad * 8);
#pragma unroll
      for (int ms = 0; ms < 4; ++ms)
        acc[ms][ns] = __builtin_amdgcn_mfma_f32_16x16x32_bf16(a[ms], b, acc[ms][ns], 0, 0, 0);
    }
  }

  // C -> LDS (XOR-swizzled for 16B reads)
#pragma unroll
  for (int ns = 0; ns < 2; ++ns) {
    const int col = wn * 32 + ns * 16 + l15;
#pragma unroll
    for (int ms = 0; ms < 4; ++ms) {
      const int r0 = wm * 64 + ms * 16 + quad * 4;
#pragma unroll
      for (int r = 0; r < 4; ++r) {
        const int row = r0 + r;
        cbuf[row * 128 + (((col >> 3) ^ (row & 15)) * 8) + (col & 7)] = (__bf16)acc[ms][ns][r];
      }
    }
  }
  __syncthreads();

#pragma unroll
  for (int i = 0; i < 4; ++i) {
    const int row = i * 32 + rbase;
    bf16x8 cv = ld8(cbuf + row * 128 + ((c15 ^ (row & 15)) * 8));
    bf16x8 o;
#pragma unroll
    for (int j = 0; j < 8; ++j) {
      float v = (float)gp[i][j] + (float)cv[j];
      o[j] = (__bf16)(v > 0.f ? v : 0.f);
    }
    st8(h + (base + row) * 128 + c15 * 8, o);
  }
}

// ---- update: h[e] = relu(gW[src[e]] - (h@Wu)[e^1] + h[e]) ----
// Round-3 config (best measured): 8-wave split, staged LDS h tile + separate
// 32KB cbuf, all gW gathers prefetched, residual from the intact h-stage,
// 2 barriers.
__global__ __launch_bounds__(512) void k_update(
    __bf16* __restrict__ h, const int* __restrict__ esrc,
    const __bf16* __restrict__ WuT, const __bf16* __restrict__ gW)
{
  __shared__ __align__(16) __bf16 smem[128 * 128];  // 32KB staged h tile
  __shared__ __align__(16) __bf16 cbuf[128 * 128];  // 32KB hWu roundtrip
  const int tid = threadIdx.x;
  const int lane = tid & 63, wave = tid >> 6;
  const int l15 = lane & 15, quad = lane >> 4;
  const int wm = wave >> 2, wn = wave & 3;   // wm: row half, wn: 32-col quarter
  const long base = (long)blockIdx.x * TILE;

  // src indices first (independent, coalesced)
  const int c15 = tid & 15, rbase = tid >> 4;        // rbase 0..31
  int srcv[4];
#pragma unroll
  for (int i = 0; i < 4; ++i) srcv[i] = esrc[base + i * 32 + rbase];

  // stage h tile: each wave 16 rows, 16B-chunk XOR swizzle
#pragma unroll
  for (int j = 0; j < 4; ++j) {
    const int r = wave * 16 + j * 4 + (lane >> 4);
    const int cd = (lane & 15) ^ (r & 15);
    async16(h + (base + r) * 128 + cd * 8, smem + (wave * 16 + j * 4) * 128);
  }

  // all gW gathers in flight before the barrier
  bf16x8 gp[4];
#pragma unroll
  for (int i = 0; i < 4; ++i) gp[i] = ld8(gW + (long)srcv[i] * 128 + c15 * 8);

  __syncthreads();

  f32x4 acc[4][2] = {};
#pragma unroll
  for (int kit = 0; kit < 4; ++kit) {
    bf16x8 a[4];
#pragma unroll
    for (int ms = 0; ms < 4; ++ms) {
      const int rm = wm * 64 + ms * 16 + l15;
      a[ms] = ld8(smem + rm * 128 + (((kit * 4 + quad) ^ l15) * 8));
    }
#pragma unroll
    for (int ns = 0; ns < 2; ++ns) {
      bf16x8 b = ld8(WuT + (wn * 32 + ns * 16 + l15) * 128 + kit * 32 + quad * 8);
#pragma unroll
      for (int ms = 0; ms < 4; ++ms)
        acc[ms][ns] = __builtin_amdgcn_mfma_f32_16x16x32_bf16(a[ms], b, acc[ms][ns], 0, 0, 0);
    }
  }

  // hWu -> cbuf (XOR-swizzled); h-stage stays intact for the residual
#pragma unroll
  for (int ns = 0; ns < 2; ++ns) {
    const int col = wn * 32 + ns * 16 + l15;
#pragma unroll
    for (int ms = 0; ms < 4; ++ms) {
      const int r0 = wm * 64 + ms * 16 + quad * 4;
#pragma unroll
      for (int r = 0; r < 4; ++r) {
        const int row = r0 + r;
        cbuf[row * 128 + (((col >> 3) ^ (row & 15)) * 8) + (col & 7)] = (__bf16)acc[ms][ns][r];
      }
    }
  }
  __syncthreads();

#pragma unroll
  for (int i = 0; i < 4; ++i) {
    const int row = i * 32 + rbase;
    const int rowr = row ^ 1;  // rev(e) = e^1, pair-aligned within tile
    bf16x8 cv = ld8(cbuf + rowr * 128 + ((c15 ^ (rowr & 15)) * 8));
    bf16x8 hv = ld8(smem + row * 128 + ((c15 ^ (row & 15)) * 8));
    bf16x8 o;
#pragma unroll
    for (int j = 0; j < 8; ++j) {
      float v = (float)gp[i][j] - (float)cv[j] + (float)hv[j];
      o[j] = (__bf16)(v > 0.f ? v : 0.f);
    }
    st8(h + (base + row) * 128 + c15 * 8, o);
  }
}

// ---- final (swapped): out = relu([nf | agg(h4)] @ Wf + bf), 16B f32 stores ----
__global__ __launch_bounds__(256) void k_final(
    const __bf16* __restrict__ nfbf, const __bf16* __restrict__ aggbf,
    const __bf16* __restrict__ WfT, const float* __restrict__ bfb,
    float* __restrict__ out)
{
  const int tid = threadIdx.x;
  const int lane = tid & 63, wave = tid >> 6;
  const int l15 = lane & 15, quad = lane >> 4;
  const int wm = wave >> 1, wn = wave & 1;
  const int base = blockIdx.x * TILE;

  int rowm[4];
#pragma unroll
  for (int ms = 0; ms < 4; ++ms) {
    int nd = base + wm * 64 + ms * 16 + l15;
    rowm[ms] = nd < N_NODES ? nd : (N_NODES - 1);
  }
  f32x4 acc[4][4] = {};
#pragma unroll
  for (int kit = 0; kit < 8; ++kit) {
    const int koff = kit * 32 + quad * 8;
    bf16x8 b[4];
#pragma unroll
    for (int ms = 0; ms < 4; ++ms)
      b[ms] = (kit < 4) ? ld8(nfbf + (long)rowm[ms] * 128 + koff)
                        : ld8(aggbf + (long)rowm[ms] * 128 + (koff - 128));
#pragma unroll
    for (int ns = 0; ns < 4; ++ns) {
      bf16x8 a = ld8(WfT + (wn * 64 + ns * 16 + l15) * 256 + koff);
#pragma unroll
      for (int ms = 0; ms < 4; ++ms)
        acc[ms][ns] = __builtin_amdgcn_mfma_f32_16x16x32_bf16(a, b[ms], acc[ms][ns], 0, 0, 0);
    }
  }
#pragma unroll
  for (int ns = 0; ns < 4; ++ns) {
    const int col = wn * 64 + ns * 16 + quad * 4;
    const f32x4 bv = *(const f32x4*)(bfb + col);
#pragma unroll
    for (int ms = 0; ms < 4; ++ms) {
      const int node = base + wm * 64 + ms * 16 + l15;
      if (node < N_NODES) {
        f32x4 o;
#pragma unroll
        for (int j = 0; j < 4; ++j) {
          float v = acc[ms][ns][j] + bv[j];
          o[j] = v > 0.f ? v : 0.f;
        }
        *(f32x4*)(out + (long)node * 128 + col) = o;
      }
    }
  }
}

extern "C" void kernel_launch(void* const* d_in, const int* in_sizes, int n_in,
                              void* d_out, int out_size, void* d_ws, size_t ws_size,
                              hipStream_t stream) {
  const float* nf   = (const float*)d_in[0];
  const float* ef   = (const float*)d_in[1];
  const int*   esrc = (const int*)d_in[2];
  const int*   edst = (const int*)d_in[3];
  const float* Wi   = (const float*)d_in[4];
  const float* bi   = (const float*)d_in[5];
  const float* Wu   = (const float*)d_in[6];
  const float* bu   = (const float*)d_in[7];
  const float* Wf   = (const float*)d_in[8];
  const float* bfb  = (const float*)d_in[9];
  float* out = (float*)d_out;

  char* ws = (char*)d_ws;
  __bf16* h      = (__bf16*)(ws);                  // 409,600,000 B
  __bf16* aggbf  = (__bf16*)(ws + 409600000L);     //  12,800,000 B
  __bf16* nfbf   = (__bf16*)(ws + 422400000L);     //  12,800,000 B
  __bf16* WiT    = (__bf16*)(ws + 435200000L);     //      40,960 B
  __bf16* WuT    = (__bf16*)(ws + 435240960L);     //      32,768 B
  __bf16* WfT    = (__bf16*)(ws + 435273728L);     //      65,536 B
  int*    cnt    = (int*)(ws + 435339264L);        //     200,000 B
  int*    cursor = (int*)(ws + 435539264L);        //     200,000 B (zrow after k_fill)
  int*    bsum   = (int*)(ws + 435739264L);        //         256 B
  int*    eidx   = (int*)(ws + 435739520L);        //   6,400,000 B
  __bf16* g      = (__bf16*)(ws + 442139520L);     //  12,800,000 B (q then gW, bf16)

  const long NV = (long)N_NODES * 128;
  const int  NGB = (N_NODES + TILE - 1) / TILE;    // 391

  hipLaunchKernelGGL(k_prep_w, dim3(272), dim3(256), 0, stream, Wi, Wu, Wf, WiT, WuT, WfT);
  hipLaunchKernelGGL(k_cvt, dim3(3125), dim3(256), 0, stream, nf, nfbf, NV);
  // CSR build
  hipMemsetAsync(cnt, 0, 200000, stream);
  hipLaunchKernelGGL(k_hist, dim3(N_EDGES / 256), dim3(256), 0, stream, edst, cnt);
  hipLaunchKernelGGL(k_scan1, dim3(49), dim3(1024), 0, stream, cnt, bsum, N_NODES);
  hipLaunchKernelGGL(k_scan2, dim3(1), dim3(64), 0, stream, bsum, 49);
  hipLaunchKernelGGL(k_scan3, dim3(196), dim3(256), 0, stream, cnt, bsum, cursor, N_NODES);
  hipLaunchKernelGGL(k_fill, dim3(N_EDGES / 256), dim3(256), 0, stream, edst, cursor, eidx);
  // cursor is dead after k_fill; its first 256B become the zero row for k_agg
  hipMemsetAsync(cursor, 0, 256, stream);
  const __bf16* zrow = (const __bf16*)cursor;

  // q = nf @ Wi[0:128] + bi (per node, bf16), then per-edge init with K=32 ef slice
  hipLaunchKernelGGL(k_nodegemm, dim3(NGB), dim3(256), 0, stream, nfbf, WiT, 160, bi, g, N_NODES);
  hipLaunchKernelGGL(k_init, dim3(N_EDGES / TILE), dim3(512), 0, stream, ef, esrc, WiT, g, h);

  for (int t = 0; t < 4; ++t) {
    hipLaunchKernelGGL(k_agg, dim3(N_NODES / 4), dim3(256), 0, stream, h, cnt, bsum, eidx, zrow, aggbf);
    hipLaunchKernelGGL(k_nodegemm, dim3(NGB), dim3(256), 0, stream, aggbf, WuT, 128, bu, g, N_NODES);
    hipLaunchKernelGGL(k_update, dim3(N_EDGES / TILE), dim3(512), 0, stream, h, esrc, WuT, g);
  }
  hipLaunchKernelGGL(k_agg, dim3(N_NODES / 4), dim3(256), 0, stream, h, cnt, bsum, eidx, zrow, aggbf);
  hipLaunchKernelGGL(k_final, dim3(NGB), dim3(256), 0, stream, nfbf, aggbf, WfT, bfb, out);
}